// Round 9
// baseline (174.470 us; speedup 1.0000x reference)
//
#include <hip/hip_runtime.h>
#include <math.h>

#define A_ 5
#define C_ 20
#define N_ 64
#define H_ 52
#define W_ 52
#define HW_ (H_ * W_)        // 2704
#define M_ 32
#define CH_ (A_ * (5 + C_))  // 125
#define CPB 64               // cells per block = 64 lanes x 1 cell
#define NBX ((HW_ + CPB - 1) / CPB)   // 43
#define NBLK (NBX * N_)               // 2752

// R8 with the spill fixed: __launch_bounds__(64, 1) lets the allocator keep
// the 125-channel burst in registers (R8's VGPR_Count=60 + 67.8MB scratch
// WRITE proved the S[5][20] array spilled). One thread per cell, all 125
// channels loaded in ONE up-front burst (~32KB in flight per wave,
// overlapping the whole compute span); winner's scores selected from
// registers via statically-indexed cndmasks. No LDS, no barriers.
__global__ __launch_bounds__(64, 1) void yolo_main(
    const float* __restrict__ x,       // (N, 125, H, W)
    const float* __restrict__ anchors, // (5, 2)
    const float* __restrict__ gt,      // (N, 32, 4)
    const int* __restrict__ glab,      // (N, 32)
    const void* img_h_p, const void* img_w_p,
    float* __restrict__ ws)            // SoA: (3, NBLK)
{
    const int lane = threadIdx.x;
    const int n    = blockIdx.y;
    const int cell = blockIdx.x * CPB + lane;
    const bool valid = cell < HW_;

    int ibw = *(const int*)img_w_p;
    float img_w = (ibw > 0 && ibw < 1000000) ? (float)ibw : *(const float*)img_w_p;
    int ibh = *(const int*)img_h_p;
    float img_h = (ibh > 0 && ibh < 1000000) ? (float)ibh : *(const float*)img_h_p;
    const float sx = img_w / (float)W_;
    const float sy = img_h / (float)H_;

    float obj = 0.f, bbx = 0.f, clf = 0.f;

    if (valid) {
        const size_t base = (size_t)n * CH_ * HW_ + cell;

        // ---- ONE burst: all 125 channel loads issued back-to-back ----
        float t[A_][5];      // box channels
        float S[A_][C_];     // score channels (100 VGPRs, live to the end)
        #pragma unroll
        for (int a = 0; a < A_; ++a) {
            #pragma unroll
            for (int v = 0; v < 5; ++v)
                t[a][v] = x[base + (size_t)(a * 25 + v) * HW_];
            #pragma unroll
            for (int j = 0; j < C_; ++j)
                S[a][j] = x[base + (size_t)(a * 25 + 5 + j) * HW_];
        }

        const int wi = cell % W_;
        const int hi = cell / W_;

        // ---- 5 boxes in registers ----
        float X1[A_], Y1[A_], X2[A_], Y2[A_], AP[A_], OVv[A_];
        #pragma unroll
        for (int a = 0; a < A_; ++a) {
            float ax = anchors[2 * a];        // uniform scalar loads
            float ay = anchors[2 * a + 1];
            float bx = 1.f / (1.f + __expf(-t[a][0])) + (float)wi * sx;
            float by = 1.f / (1.f + __expf(-t[a][1])) + (float)hi * sy;
            float bw = sx * ax * __expf(t[a][2]);
            float bh = sy * ay * __expf(t[a][3]);
            X1[a] = bx; Y1[a] = by; X2[a] = bx + bw; Y2[a] = by + bh;
            AP[a] = (X2[a] - X1[a]) * (Y2[a] - Y1[a]);   // match reference
            OVv[a] = 1.f / (1.f + __expf(-t[a][4]));
        }

        // ---- single m-loop, 5 independent argmax chains (5-way ILP) ----
        float BIv[A_] = {0.f, 0.f, 0.f, 0.f, 0.f};
        float BUv[A_] = {1.f, 1.f, 1.f, 1.f, 1.f};
        int   BMv[A_] = {0, 0, 0, 0, 0};
        const float4* gtv = (const float4*)(gt + (size_t)n * M_ * 4);
        #pragma unroll 8
        for (int m = 0; m < M_; ++m) {
            float4 g = gtv[m];                // wave-uniform -> scalar path
            float area = (g.z - g.x) * (g.w - g.y);
            #pragma unroll
            for (int a = 0; a < A_; ++a) {
                float wq = fminf(X2[a], g.z) - fmaxf(X1[a], g.x);
                float hq = fminf(Y2[a], g.w) - fmaxf(Y1[a], g.y);
                wq = fmaxf(wq, 0.f);
                hq = fmaxf(hq, 0.f);
                float inter = wq * hq;
                float uni = AP[a] + area - inter;
                if (inter * BUv[a] > BIv[a] * uni) {
                    BIv[a] = inter; BUv[a] = uni; BMv[a] = m;
                }
            }
        }

        // ---- select winning anchor in registers (first-max semantics) ----
        float Bi = BIv[0], Bu = BUv[0], O = OVv[0];
        float wx1 = X1[0], wy1 = Y1[0], wx2 = X2[0], wy2 = Y2[0];
        int Ba = 0, Bm = BMv[0];
        float bomax = OVv[0];
        #pragma unroll
        for (int a = 1; a < A_; ++a) {
            bomax = fmaxf(bomax, OVv[a]);
            if (BIv[a] * Bu > Bi * BUv[a]) {
                Bi = BIv[a]; Bu = BUv[a]; O = OVv[a];
                wx1 = X1[a]; wy1 = Y1[a]; wx2 = X2[a]; wy2 = Y2[a];
                Ba = a; Bm = BMv[a];
            }
        }

        if (Bi > 0.f) {
            float d = O - Bi / Bu;
            obj = d * d;

            float4 g = ((const float4*)gt)[n * M_ + Bm];
            int lab = glab[n * M_ + Bm];
            float d0 = wx1 - g.x;
            float d1 = wy1 - g.y;
            float d2 = sqrtf(wx2) - sqrtf(g.z);
            float d3 = sqrtf(wy2) - sqrtf(g.w);
            bbx = d0 * d0 + d1 * d1 + d2 * d2 + d3 * d3;

            // ---- CE from registers: statically-indexed 5-way select ----
            float mx = -1e30f, se = 0.f, scl = 0.f;
            float sc[C_];
            #pragma unroll
            for (int j = 0; j < C_; ++j) {
                float v = S[0][j];
                v = (Ba == 1) ? S[1][j] : v;
                v = (Ba == 2) ? S[2][j] : v;
                v = (Ba == 3) ? S[3][j] : v;
                v = (Ba == 4) ? S[4][j] : v;
                sc[j] = v;
                mx = fmaxf(mx, v);
            }
            #pragma unroll
            for (int j = 0; j < C_; ++j) {
                se += __expf(sc[j] - mx);
                scl = (j == lab) ? sc[j] : scl;
            }
            clf = mx + __logf(se) - scl;
        } else {
            obj = 0.5f * bomax * bomax;
        }
    }

    // ---- single-wave reduce, one SoA write ----
    #pragma unroll
    for (int off = 32; off > 0; off >>= 1) {
        obj += __shfl_down(obj, off, 64);
        bbx += __shfl_down(bbx, off, 64);
        clf += __shfl_down(clf, off, 64);
    }
    if (lane == 0) {
        const int bid = blockIdx.y * gridDim.x + blockIdx.x;
        ws[0 * NBLK + bid] = obj;
        ws[1 * NBLK + bid] = bbx;
        ws[2 * NBLK + bid] = clf;
    }
}

__global__ __launch_bounds__(1024) void yolo_reduce(
    const float* __restrict__ ws, float* __restrict__ out)
{
    __shared__ float s_red[16][3];
    const int tid = threadIdx.x;
    float o = 0.f, b = 0.f, c = 0.f;
    for (int e = tid; e < NBLK; e += 1024) {
        o += ws[0 * NBLK + e];
        b += ws[1 * NBLK + e];
        c += ws[2 * NBLK + e];
    }
    #pragma unroll
    for (int off = 32; off > 0; off >>= 1) {
        o += __shfl_down(o, off, 64);
        b += __shfl_down(b, off, 64);
        c += __shfl_down(c, off, 64);
    }
    const int wid = tid >> 6;
    if ((tid & 63) == 0) {
        s_red[wid][0] = o; s_red[wid][1] = b; s_red[wid][2] = c;
    }
    __syncthreads();
    if (tid == 0) {
        float oo = 0.f, bb = 0.f, cc = 0.f;
        #pragma unroll
        for (int w = 0; w < 16; ++w) {
            oo += s_red[w][0]; bb += s_red[w][1]; cc += s_red[w][2];
        }
        out[0] = oo; out[1] = bb; out[2] = cc;
    }
}

extern "C" void kernel_launch(void* const* d_in, const int* in_sizes, int n_in,
                              void* d_out, int out_size, void* d_ws, size_t ws_size,
                              hipStream_t stream) {
    (void)in_sizes; (void)n_in; (void)out_size; (void)ws_size;
    const float* x    = (const float*)d_in[0];
    const float* anch = (const float*)d_in[1];
    const float* gt   = (const float*)d_in[2];
    const int*   gl   = (const int*)d_in[3];
    const void*  ih   = d_in[4];
    const void*  iw   = d_in[5];
    float* out = (float*)d_out;
    float* ws  = (float*)d_ws;

    dim3 grid(NBX, N_);
    yolo_main<<<grid, dim3(64), 0, stream>>>(x, anch, gt, gl, ih, iw, ws);
    yolo_reduce<<<1, 1024, 0, stream>>>(ws, out);
}

// Round 10
// 152.317 us; speedup vs baseline: 1.1454x; 1.1454x over previous
//
#include <hip/hip_runtime.h>
#include <math.h>

#define A_ 5
#define C_ 20
#define N_ 64
#define H_ 52
#define W_ 52
#define HW_ (H_ * W_)        // 2704
#define M_ 32
#define CH_ (A_ * (5 + C_))  // 125
#define CPB 64               // cells per block = 64 lanes x 1 cell
#define NBX ((HW_ + CPB - 1) / CPB)   // 43
#define NBLK (NBX * N_)               // 2752

// R6 champion + streamed CE: one thread per cell owning all 5 anchors.
// Per anchor, the 20 score channels are consumed into lse[a] AS THEY STREAM
// (values die immediately -> no register-pressure spill, proven by R3's
// VGPR=80/no-scratch counters). After the in-register argmax, the CE needs
// only ONE hot reload (sc[label]) instead of a dependent 20-load gather —
// removing the last exposed memory-latency tail. No LDS, no barriers.
__global__ __launch_bounds__(64) void yolo_main(
    const float* __restrict__ x,       // (N, 125, H, W)
    const float* __restrict__ anchors, // (5, 2)
    const float* __restrict__ gt,      // (N, 32, 4)
    const int* __restrict__ glab,      // (N, 32)
    const void* img_h_p, const void* img_w_p,
    float* __restrict__ ws)            // SoA: (3, NBLK)
{
    const int lane = threadIdx.x;
    const int n    = blockIdx.y;
    const int cell = blockIdx.x * CPB + lane;
    const bool valid = cell < HW_;

    int ibw = *(const int*)img_w_p;
    float img_w = (ibw > 0 && ibw < 1000000) ? (float)ibw : *(const float*)img_w_p;
    int ibh = *(const int*)img_h_p;
    float img_h = (ibh > 0 && ibh < 1000000) ? (float)ibh : *(const float*)img_h_p;
    const float sx = img_w / (float)W_;
    const float sy = img_h / (float)H_;

    float obj = 0.f, bbx = 0.f, clf = 0.f;

    if (valid) {
        const size_t base = (size_t)n * CH_ * HW_ + cell;
        const int wi = cell % W_;
        const int hi = cell / W_;

        // ---- streamed per-anchor pass: box + lse, short live ranges ----
        float X1[A_], Y1[A_], X2[A_], Y2[A_], AP[A_], OVv[A_], LSE[A_];
        #pragma unroll
        for (int a = 0; a < A_; ++a) {
            const size_t pb = base + (size_t)(a * 25) * HW_;
            float t0 = x[pb];
            float t1 = x[pb + (size_t)HW_];
            float t2 = x[pb + 2 * (size_t)HW_];
            float t3 = x[pb + 3 * (size_t)HW_];
            float t4 = x[pb + 4 * (size_t)HW_];
            float S[C_];
            #pragma unroll
            for (int j = 0; j < C_; ++j)
                S[j] = x[pb + (size_t)(5 + j) * HW_];

            float ax = anchors[2 * a];        // uniform scalar loads
            float ay = anchors[2 * a + 1];
            float bx = 1.f / (1.f + __expf(-t0)) + (float)wi * sx;
            float by = 1.f / (1.f + __expf(-t1)) + (float)hi * sy;
            float bw = sx * ax * __expf(t2);
            float bh = sy * ay * __expf(t3);
            X1[a] = bx; Y1[a] = by; X2[a] = bx + bw; Y2[a] = by + bh;
            AP[a] = (X2[a] - X1[a]) * (Y2[a] - Y1[a]);   // match reference
            OVv[a] = 1.f / (1.f + __expf(-t4));

            float mx = S[0];
            #pragma unroll
            for (int j = 1; j < C_; ++j) mx = fmaxf(mx, S[j]);
            float se = 0.f;
            #pragma unroll
            for (int j = 0; j < C_; ++j) se += __expf(S[j] - mx);
            LSE[a] = mx + __logf(se);         // S dies here — no long liveness
        }

        // ---- single m-loop, 5 independent argmax chains (5-way ILP) ----
        float BIv[A_] = {0.f, 0.f, 0.f, 0.f, 0.f};
        float BUv[A_] = {1.f, 1.f, 1.f, 1.f, 1.f};
        int   BMv[A_] = {0, 0, 0, 0, 0};
        const float4* gtv = (const float4*)(gt + (size_t)n * M_ * 4);
        #pragma unroll 8
        for (int m = 0; m < M_; ++m) {
            float4 g = gtv[m];                // wave-uniform -> scalar path
            float area = (g.z - g.x) * (g.w - g.y);
            #pragma unroll
            for (int a = 0; a < A_; ++a) {
                float wq = fminf(X2[a], g.z) - fmaxf(X1[a], g.x);
                float hq = fminf(Y2[a], g.w) - fmaxf(Y1[a], g.y);
                wq = fmaxf(wq, 0.f);
                hq = fmaxf(hq, 0.f);
                float inter = wq * hq;
                float uni = AP[a] + area - inter;
                if (inter * BUv[a] > BIv[a] * uni) {
                    BIv[a] = inter; BUv[a] = uni; BMv[a] = m;
                }
            }
        }

        // ---- select winning anchor in registers (first-max semantics) ----
        float Bi = BIv[0], Bu = BUv[0], O = OVv[0], Lw = LSE[0];
        float wx1 = X1[0], wy1 = Y1[0], wx2 = X2[0], wy2 = Y2[0];
        int Ba = 0, Bm = BMv[0];
        float bomax = OVv[0];
        #pragma unroll
        for (int a = 1; a < A_; ++a) {
            bomax = fmaxf(bomax, OVv[a]);
            if (BIv[a] * Bu > Bi * BUv[a]) {
                Bi = BIv[a]; Bu = BUv[a]; O = OVv[a]; Lw = LSE[a];
                wx1 = X1[a]; wy1 = Y1[a]; wx2 = X2[a]; wy2 = Y2[a];
                Ba = a; Bm = BMv[a];
            }
        }

        if (Bi > 0.f) {
            float d = O - Bi / Bu;
            obj = d * d;

            float4 g = ((const float4*)gt)[n * M_ + Bm];
            int lab = glab[n * M_ + Bm];
            float d0 = wx1 - g.x;
            float d1 = wy1 - g.y;
            float d2 = sqrtf(wx2) - sqrtf(g.z);
            float d3 = sqrtf(wy2) - sqrtf(g.w);
            bbx = d0 * d0 + d1 * d1 + d2 * d2 + d3 * d3;

            // ONE hot reload of the winner's label score (line is L3-resident)
            float scl = x[base + (size_t)(Ba * 25 + 5 + lab) * HW_];
            clf = Lw - scl;
        } else {
            obj = 0.5f * bomax * bomax;
        }
    }

    // ---- single-wave reduce, one SoA write ----
    #pragma unroll
    for (int off = 32; off > 0; off >>= 1) {
        obj += __shfl_down(obj, off, 64);
        bbx += __shfl_down(bbx, off, 64);
        clf += __shfl_down(clf, off, 64);
    }
    if (lane == 0) {
        const int bid = blockIdx.y * gridDim.x + blockIdx.x;
        ws[0 * NBLK + bid] = obj;
        ws[1 * NBLK + bid] = bbx;
        ws[2 * NBLK + bid] = clf;
    }
}

__global__ __launch_bounds__(1024) void yolo_reduce(
    const float* __restrict__ ws, float* __restrict__ out)
{
    __shared__ float s_red[16][3];
    const int tid = threadIdx.x;
    float o = 0.f, b = 0.f, c = 0.f;
    for (int e = tid; e < NBLK; e += 1024) {
        o += ws[0 * NBLK + e];
        b += ws[1 * NBLK + e];
        c += ws[2 * NBLK + e];
    }
    #pragma unroll
    for (int off = 32; off > 0; off >>= 1) {
        o += __shfl_down(o, off, 64);
        b += __shfl_down(b, off, 64);
        c += __shfl_down(c, off, 64);
    }
    const int wid = tid >> 6;
    if ((tid & 63) == 0) {
        s_red[wid][0] = o; s_red[wid][1] = b; s_red[wid][2] = c;
    }
    __syncthreads();
    if (tid == 0) {
        float oo = 0.f, bb = 0.f, cc = 0.f;
        #pragma unroll
        for (int w = 0; w < 16; ++w) {
            oo += s_red[w][0]; bb += s_red[w][1]; cc += s_red[w][2];
        }
        out[0] = oo; out[1] = bb; out[2] = cc;
    }
}

extern "C" void kernel_launch(void* const* d_in, const int* in_sizes, int n_in,
                              void* d_out, int out_size, void* d_ws, size_t ws_size,
                              hipStream_t stream) {
    (void)in_sizes; (void)n_in; (void)out_size; (void)ws_size;
    const float* x    = (const float*)d_in[0];
    const float* anch = (const float*)d_in[1];
    const float* gt   = (const float*)d_in[2];
    const int*   gl   = (const int*)d_in[3];
    const void*  ih   = d_in[4];
    const void*  iw   = d_in[5];
    float* out = (float*)d_out;
    float* ws  = (float*)d_ws;

    dim3 grid(NBX, N_);
    yolo_main<<<grid, dim3(64), 0, stream>>>(x, anch, gt, gl, ih, iw, ws);
    yolo_reduce<<<1, 1024, 0, stream>>>(ws, out);
}

// Round 11
// 141.269 us; speedup vs baseline: 1.2350x; 1.0782x over previous
//
#include <hip/hip_runtime.h>
#include <math.h>

#define A_ 5
#define C_ 20
#define N_ 64
#define H_ 52
#define W_ 52
#define HW_ (H_ * W_)        // 2704
#define M_ 32
#define CH_ (A_ * (5 + C_))  // 125
#define CPB 64               // cells per block = 64 lanes x 1 cell
#define NBX ((HW_ + CPB - 1) / CPB)   // 43
#define NBLK (NBX * N_)               // 2752

// Session champion (R6, 140.96us): one thread per CELL owning all 5 anchors.
// 64-thread (1-wave) blocks: no LDS, no barriers, no idle tail waves.
// 25 coalesced loads up front, 5 independent IoU chains in the single m-loop
// (5-way ILP), winner selected in registers, CE computed exactly once
// (winner anchor only, lazy dependent gather — measured faster than all
// speculative-CE variants: R2/R5/R10).
__global__ __launch_bounds__(64) void yolo_main(
    const float* __restrict__ x,       // (N, 125, H, W)
    const float* __restrict__ anchors, // (5, 2)
    const float* __restrict__ gt,      // (N, 32, 4)
    const int* __restrict__ glab,      // (N, 32)
    const void* img_h_p, const void* img_w_p,
    float* __restrict__ ws)            // SoA: (3, NBLK)
{
    const int lane = threadIdx.x;
    const int n    = blockIdx.y;
    const int cell = blockIdx.x * CPB + lane;
    const bool valid = cell < HW_;

    int ibw = *(const int*)img_w_p;
    float img_w = (ibw > 0 && ibw < 1000000) ? (float)ibw : *(const float*)img_w_p;
    int ibh = *(const int*)img_h_p;
    float img_h = (ibh > 0 && ibh < 1000000) ? (float)ibh : *(const float*)img_h_p;
    const float sx = img_w / (float)W_;
    const float sy = img_h / (float)H_;

    float obj = 0.f, bbx = 0.f, clf = 0.f;

    if (valid) {
        const size_t base = (size_t)n * CH_ * HW_ + cell;

        // ---- bulk-issue all 25 box-channel loads (coalesced 256B each) ----
        float t[A_][5];
        #pragma unroll
        for (int a = 0; a < A_; ++a)
            #pragma unroll
            for (int v = 0; v < 5; ++v)
                t[a][v] = x[base + (size_t)(a * 25 + v) * HW_];

        const int wi = cell % W_;
        const int hi = cell / W_;

        // ---- 5 boxes in registers ----
        float X1[A_], Y1[A_], X2[A_], Y2[A_], AP[A_], OVv[A_];
        #pragma unroll
        for (int a = 0; a < A_; ++a) {
            float ax = anchors[2 * a];        // uniform scalar loads
            float ay = anchors[2 * a + 1];
            float bx = 1.f / (1.f + __expf(-t[a][0])) + (float)wi * sx;
            float by = 1.f / (1.f + __expf(-t[a][1])) + (float)hi * sy;
            float bw = sx * ax * __expf(t[a][2]);
            float bh = sy * ay * __expf(t[a][3]);
            X1[a] = bx; Y1[a] = by; X2[a] = bx + bw; Y2[a] = by + bh;
            AP[a] = (X2[a] - X1[a]) * (Y2[a] - Y1[a]);   // match reference
            OVv[a] = 1.f / (1.f + __expf(-t[a][4]));
        }

        // ---- single m-loop, 5 independent argmax chains ----
        float BIv[A_] = {0.f, 0.f, 0.f, 0.f, 0.f};
        float BUv[A_] = {1.f, 1.f, 1.f, 1.f, 1.f};
        int   BMv[A_] = {0, 0, 0, 0, 0};
        const float4* gtv = (const float4*)(gt + (size_t)n * M_ * 4);
        #pragma unroll 8
        for (int m = 0; m < M_; ++m) {
            float4 g = gtv[m];                // wave-uniform -> scalar path
            float area = (g.z - g.x) * (g.w - g.y);
            #pragma unroll
            for (int a = 0; a < A_; ++a) {
                float wq = fminf(X2[a], g.z) - fmaxf(X1[a], g.x);
                float hq = fminf(Y2[a], g.w) - fmaxf(Y1[a], g.y);
                wq = fmaxf(wq, 0.f);
                hq = fmaxf(hq, 0.f);
                float inter = wq * hq;
                float uni = AP[a] + area - inter;
                if (inter * BUv[a] > BIv[a] * uni) {
                    BIv[a] = inter; BUv[a] = uni; BMv[a] = m;
                }
            }
        }

        // ---- select winning anchor in registers (first-max semantics) ----
        float Bi = BIv[0], Bu = BUv[0], O = OVv[0];
        float wx1 = X1[0], wy1 = Y1[0], wx2 = X2[0], wy2 = Y2[0];
        int Ba = 0, Bm = BMv[0];
        float bomax = OVv[0];
        #pragma unroll
        for (int a = 1; a < A_; ++a) {
            bomax = fmaxf(bomax, OVv[a]);
            if (BIv[a] * Bu > Bi * BUv[a]) {
                Bi = BIv[a]; Bu = BUv[a]; O = OVv[a];
                wx1 = X1[a]; wy1 = Y1[a]; wx2 = X2[a]; wy2 = Y2[a];
                Ba = a; Bm = BMv[a];
            }
        }

        if (Bi > 0.f) {
            float d = O - Bi / Bu;
            obj = d * d;

            float4 g = ((const float4*)gt)[n * M_ + Bm];
            int lab = glab[n * M_ + Bm];
            float d0 = wx1 - g.x;
            float d1 = wy1 - g.y;
            float d2 = sqrtf(wx2) - sqrtf(g.z);
            float d3 = sqrtf(wy2) - sqrtf(g.w);
            bbx = d0 * d0 + d1 * d1 + d2 * d2 + d3 * d3;

            // ---- CE exactly once: winner's 20 scores (bulk-issued) ----
            const size_t sb = base + (size_t)(Ba * 25 + 5) * HW_;
            float sc[C_];
            #pragma unroll
            for (int j = 0; j < C_; ++j)
                sc[j] = x[sb + (size_t)j * HW_];
            float mx = sc[0];
            #pragma unroll
            for (int j = 1; j < C_; ++j) mx = fmaxf(mx, sc[j]);
            float se = 0.f, scl = sc[0];
            #pragma unroll
            for (int j = 0; j < C_; ++j) {
                se += __expf(sc[j] - mx);
                scl = (j == lab) ? sc[j] : scl;
            }
            clf = mx + __logf(se) - scl;
        } else {
            obj = 0.5f * bomax * bomax;
        }
    }

    // ---- single-wave reduce, one SoA write ----
    #pragma unroll
    for (int off = 32; off > 0; off >>= 1) {
        obj += __shfl_down(obj, off, 64);
        bbx += __shfl_down(bbx, off, 64);
        clf += __shfl_down(clf, off, 64);
    }
    if (lane == 0) {
        const int bid = blockIdx.y * gridDim.x + blockIdx.x;
        ws[0 * NBLK + bid] = obj;
        ws[1 * NBLK + bid] = bbx;
        ws[2 * NBLK + bid] = clf;
    }
}

__global__ __launch_bounds__(1024) void yolo_reduce(
    const float* __restrict__ ws, float* __restrict__ out)
{
    __shared__ float s_red[16][3];
    const int tid = threadIdx.x;
    float o = 0.f, b = 0.f, c = 0.f;
    for (int e = tid; e < NBLK; e += 1024) {
        o += ws[0 * NBLK + e];
        b += ws[1 * NBLK + e];
        c += ws[2 * NBLK + e];
    }
    #pragma unroll
    for (int off = 32; off > 0; off >>= 1) {
        o += __shfl_down(o, off, 64);
        b += __shfl_down(b, off, 64);
        c += __shfl_down(c, off, 64);
    }
    const int wid = tid >> 6;
    if ((tid & 63) == 0) {
        s_red[wid][0] = o; s_red[wid][1] = b; s_red[wid][2] = c;
    }
    __syncthreads();
    if (tid == 0) {
        float oo = 0.f, bb = 0.f, cc = 0.f;
        #pragma unroll
        for (int w = 0; w < 16; ++w) {
            oo += s_red[w][0]; bb += s_red[w][1]; cc += s_red[w][2];
        }
        out[0] = oo; out[1] = bb; out[2] = cc;
    }
}

extern "C" void kernel_launch(void* const* d_in, const int* in_sizes, int n_in,
                              void* d_out, int out_size, void* d_ws, size_t ws_size,
                              hipStream_t stream) {
    (void)in_sizes; (void)n_in; (void)out_size; (void)ws_size;
    const float* x    = (const float*)d_in[0];
    const float* anch = (const float*)d_in[1];
    const float* gt   = (const float*)d_in[2];
    const int*   gl   = (const int*)d_in[3];
    const void*  ih   = d_in[4];
    const void*  iw   = d_in[5];
    float* out = (float*)d_out;
    float* ws  = (float*)d_ws;

    dim3 grid(NBX, N_);
    yolo_main<<<grid, dim3(64), 0, stream>>>(x, anch, gt, gl, ih, iw, ws);
    yolo_reduce<<<1, 1024, 0, stream>>>(ws, out);
}